// Round 2
// baseline (520.244 us; speedup 1.0000x reference)
//
#include <hip/hip_runtime.h>

#define B_  2048
#define S_  512
#define F_  64
#define H_  32
#define G_  128   // 4*H
#define D_  6     // x-tile prefetch depth (ring of 8)

__device__ __forceinline__ void gload_lds4(const float* g, float* l) {
    __builtin_amdgcn_global_load_lds(
        (const __attribute__((address_space(1))) void*)g,
        (__attribute__((address_space(3))) void*)l,
        4, 0, 0);
}

__global__ __launch_bounds__(128, 4)
void lstm_mlp_kernel(const float* __restrict__ x,
                     const float* __restrict__ Wx,
                     const float* __restrict__ Wh,
                     const float* __restrict__ bg,
                     const float* __restrict__ W1,
                     const float* __restrict__ b1,
                     const float* __restrict__ W2,
                     const float* __restrict__ b2,
                     const float* __restrict__ Wo,
                     const float* __restrict__ bo,
                     float* __restrict__ out)
{
    const int tid  = threadIdx.x;    // 0..127
    const int wid  = tid >> 6;       // wave 0: i,f columns; wave 1: g,o columns
    const int lane = tid & 63;
    const int gcol = tid;            // gate column 0..127 (i[0..31] f g o)
    const int b    = blockIdx.x;

    __shared__ float xring[8][64];
    __shared__ float hbuf[32];
    __shared__ float gbuf[64];

    // ---- register-resident weight column (96 floats/lane) ----
    float wx[F_];
#pragma unroll
    for (int f = 0; f < F_; ++f) wx[f] = Wx[f * G_ + gcol];
    float wh[H_];
#pragma unroll
    for (int k = 0; k < H_; ++k) wh[k] = Wh[k * G_ + gcol];
    const float bz = bg[gcol];

    const float* xb = x + (size_t)b * (S_ * F_);

    if (tid < 32) hbuf[tid] = 0.0f;
    if (wid == 0) {
        for (int t = 0; t < D_; ++t)
            gload_lds4(xb + t * F_ + lane, &xring[t][0]);
    }

    float cc = 0.0f;   // cell state: wave1 lanes 0..31 (lane j holds c[j])

    for (int t = 0; t < S_; ++t) {
        if (wid == 0) {
            // tile t landed (keep D_-1 younger DMAs in flight)
            asm volatile("s_waitcnt vmcnt(5)" ::: "memory");
        }
        __syncthreads();   // A: publishes xring[t&7] and hbuf (h_{t-1})

        const float4* xt = (const float4*)&xring[t & 7][0];
        const float4* hp = (const float4*)&hbuf[0];

        float z0 = bz, z1 = 0.0f;
#pragma unroll
        for (int q = 0; q < 8; ++q) {          // recurrent part: 32 FMAs
            float4 h4 = hp[q];
            z0 = fmaf(h4.x, wh[4 * q + 0], z0);
            z1 = fmaf(h4.y, wh[4 * q + 1], z1);
            z0 = fmaf(h4.z, wh[4 * q + 2], z0);
            z1 = fmaf(h4.w, wh[4 * q + 3], z1);
        }
#pragma unroll
        for (int q = 0; q < 16; ++q) {         // input part: 64 FMAs
            float4 x4 = xt[q];
            z0 = fmaf(x4.x, wx[4 * q + 0], z0);
            z1 = fmaf(x4.y, wx[4 * q + 1], z1);
            z0 = fmaf(x4.z, wx[4 * q + 2], z0);
            z1 = fmaf(x4.w, wx[4 * q + 3], z1);
        }
        float z = z0 + z1;

        float go = 0.0f;
        if (wid == 0) {
            // i (lanes<32) and f (lanes>=32): sigmoid; publish to wave1
            float s = __builtin_amdgcn_rcpf(1.0f + __expf(-z));
            gbuf[lane] = s;
            // prefetch tile t+D (clamped re-issue keeps vmcnt constant)
            int tp = t + D_; if (tp > S_ - 1) tp = S_ - 1;
            gload_lds4(xb + tp * F_ + lane, &xring[(t + D_) & 7][0]);
        } else {
            // g (lanes<32): tanh; o (lanes>=32): sigmoid
            bool lo = lane < 32;
            float zx = lo ? 2.0f * z : z;
            float s  = __builtin_amdgcn_rcpf(1.0f + __expf(-zx));
            go = lo ? 2.0f * s - 1.0f : s;
        }
        __syncthreads();   // B: publishes gbuf (i, f)

        if (wid == 1) {
            float osh = __shfl_xor(go, 32);    // lanes<32 receive o[j]
            if (lane < 32) {
                float iv = gbuf[lane];
                float fv = gbuf[32 + lane];
                cc = fmaf(fv, cc, iv * go);    // c = f*c + i*g
                float th = 2.0f * __builtin_amdgcn_rcpf(1.0f + __expf(-2.0f * cc)) - 1.0f;
                hbuf[lane] = osh * th;         // h = o * tanh(c)
            }
        }
    }
    __syncthreads();

    // ---- MLP head: 32 -> 32 -> 16 -> 3, leaky_relu(0.01) ----
    if (tid < 32) {
        float a1 = b1[tid];
#pragma unroll
        for (int k = 0; k < 32; ++k)
            a1 = fmaf(hbuf[k], W1[k * 32 + tid], a1);
        a1 = (a1 > 0.0f) ? a1 : 0.01f * a1;
        gbuf[tid] = a1;
    }
    __syncthreads();
    if (tid < 16) {
        float a2 = b2[tid];
#pragma unroll
        for (int k = 0; k < 32; ++k)
            a2 = fmaf(gbuf[k], W2[k * 16 + tid], a2);
        a2 = (a2 > 0.0f) ? a2 : 0.01f * a2;
        xring[0][tid] = a2;
    }
    __syncthreads();
    if (tid < 3) {
        float o = bo[tid];
#pragma unroll
        for (int k = 0; k < 16; ++k)
            o = fmaf(xring[0][k], Wo[k * 3 + tid], o);
        out[(size_t)b * 3 + tid] = o;
    }
}

extern "C" void kernel_launch(void* const* d_in, const int* in_sizes, int n_in,
                              void* d_out, int out_size, void* d_ws, size_t ws_size,
                              hipStream_t stream) {
    const float* x  = (const float*)d_in[0];
    const float* Wx = (const float*)d_in[1];
    const float* Wh = (const float*)d_in[2];
    const float* bg = (const float*)d_in[3];
    const float* W1 = (const float*)d_in[4];
    const float* b1 = (const float*)d_in[5];
    const float* W2 = (const float*)d_in[6];
    const float* b2 = (const float*)d_in[7];
    const float* Wo = (const float*)d_in[8];
    const float* bo = (const float*)d_in[9];
    float* out = (float*)d_out;

    hipLaunchKernelGGL(lstm_mlp_kernel, dim3(B_), dim3(128), 0, stream,
                       x, Wx, Wh, bg, W1, b1, W2, b2, Wo, bo, out);
}